// Round 8
// baseline (318.761 us; speedup 1.0000x reference)
//
#include <hip/hip_runtime.h>
#include <hip/hip_bf16.h>
#include <hip/hip_fp16.h>
#include <math.h>

typedef __hip_bfloat16 bf16;
#define NEG_SLOPE 0.2f

// ====== dtype detect (block 0) + zero deg/cursor/scan-state ==================
__global__ void k_detect_zero(const unsigned short* __restrict__ x, int* __restrict__ flag,
                              int* __restrict__ zbase, int n) {
    for (int i = blockIdx.x * blockDim.x + threadIdx.x; i < n; i += gridDim.x * blockDim.x)
        zbase[i] = 0;
    if (blockIdx.x == 0) {
        __shared__ int cnt;
        if (threadIdx.x == 0) cnt = 0;
        __syncthreads();
        int local = 0;
        for (int i = threadIdx.x; i < 2048; i += blockDim.x) {
            unsigned short w = x[2 * i];
            int e = (w >> 7) & 0xFF;
            if (e >= 0x90) local++;
        }
        atomicAdd(&cnt, local);
        __syncthreads();
        if (threadIdx.x == 0) flag[0] = (cnt > 100) ? 1 : 0;  // 1 => inputs are f32
    }
}

#define NSEG 25
struct Seg { const void* src; int n; int off; };
struct Tab { Seg s[NSEG]; };

// ====== convert weights to fp32 + count degrees ==============================
__global__ void k_convert(Tab tab, float* __restrict__ dst, const int* __restrict__ flag,
                          const int* __restrict__ dstArr, int E, int N,
                          int* __restrict__ deg) {
    int f32mode = flag[0];
    int gid = blockIdx.x * blockDim.x + threadIdx.x;
    int gsz = gridDim.x * blockDim.x;
    for (int s = 0; s < NSEG; s++) {
        Seg sg = tab.s[s];
        for (int i = gid; i < sg.n; i += gsz) {
            float v = f32mode ? ((const float*)sg.src)[i]
                              : __bfloat162float(((const bf16*)sg.src)[i]);
            dst[sg.off + i] = v;
        }
    }
    int EA = E + N;
    for (int e = gid; e < EA; e += gsz) {
        int d = (e < E) ? dstArr[e] : (e - E);
        atomicAdd(&deg[d], 1);
    }
}

// ====== single-kernel chained-lookback exclusive scan ========================
#define SFLAG (1 << 30)
__launch_bounds__(1024)
__global__ void k_scanf(const int* __restrict__ deg, int* __restrict__ offs,
                        int n, int* __restrict__ st, int nb) {
    __shared__ int ws[16];
    __shared__ int stot, sprev;
    int tile = blockIdx.x;
    int i = tile * 1024 + threadIdx.x;
    int lane = threadIdx.x & 63, wid = threadIdx.x >> 6;
    int v = (i < n) ? deg[i] : 0;
    int x = v;
    #pragma unroll
    for (int o = 1; o < 64; o <<= 1) {
        int y = __shfl_up(x, o);
        if (lane >= o) x += y;
    }
    if (lane == 63) ws[wid] = x;
    __syncthreads();
    if (wid == 0) {
        int w = (lane < 16) ? ws[lane] : 0;
        int s = w;
        #pragma unroll
        for (int o = 1; o < 16; o <<= 1) {
            int y = __shfl_up(s, o);
            if (lane >= o) s += y;
        }
        if (lane < 16) ws[lane] = s - w;
        if (lane == 15) stot = s;
    }
    __syncthreads();
    int local = ws[wid] + x - v;     // block-local exclusive
    if (threadIdx.x == 0) {
        int prev = 0;
        if (tile > 0) {
            int vv;
            while ((((vv = __hip_atomic_load(&st[tile - 1], __ATOMIC_ACQUIRE,
                                             __HIP_MEMORY_SCOPE_AGENT))) & SFLAG) == 0) {}
            prev = vv & ~SFLAG;
        }
        __hip_atomic_store(&st[tile], (prev + stot) | SFLAG, __ATOMIC_RELEASE,
                           __HIP_MEMORY_SCOPE_AGENT);
        sprev = prev;
        if (tile == nb - 1) offs[n] = prev + stot;
    }
    __syncthreads();
    if (i < n) offs[i] = sprev + local;
}

// ====== fused: CSR fill (blocks >= EB) + embed+conv1-linear (blocks < EB) ====
__launch_bounds__(256)
__global__ void k_fill_embedlin(// fill args
                                const int* __restrict__ srcArr, const int* __restrict__ dstArr,
                                int E, int N, const int* __restrict__ offs,
                                int* __restrict__ cursor, int* __restrict__ csr,
                                // embedlin args
                                const void* __restrict__ xraw, const int* __restrict__ flag,
                                const float* __restrict__ aeW, const float* __restrict__ aeb,
                                const float* __restrict__ Wl, const float* __restrict__ bl,
                                const float* __restrict__ Wr, const float* __restrict__ br,
                                __half* __restrict__ outl, float* __restrict__ outr,
                                int EB) {
    __shared__ float xs[100 * 36];
    __shared__ float axs[32 * 36];
    if (blockIdx.x >= EB) {
        // ---------------- CSR fill path ----------------
        int e = (blockIdx.x - EB) * 256 + threadIdx.x;
        int EA = E + N;
        if (e >= EA) return;
        int d, s;
        if (e < E) { d = dstArr[e]; s = srcArr[e]; } else { d = s = e - E; }
        int pos = atomicAdd(&cursor[d], 1);
        csr[offs[d] + pos] = s;
        return;
    }
    // ---------------- embed + dual linear path ----------------
    constexpr int NTP = 36;
    int t = threadIdx.x, nb = blockIdx.x * 32;
    // stage x tile transposed
    if (flag[0]) {
        const float4* x4 = (const float4*)xraw;
        for (int idx = t; idx < 32 * 25; idx += 256) {
            int node = idx / 25, k4 = idx % 25;
            float4 v = x4[(size_t)(nb + node) * 25 + k4];
            xs[(k4 * 4 + 0) * NTP + node] = v.x;
            xs[(k4 * 4 + 1) * NTP + node] = v.y;
            xs[(k4 * 4 + 2) * NTP + node] = v.z;
            xs[(k4 * 4 + 3) * NTP + node] = v.w;
        }
    } else {
        const ushort4* xu = (const ushort4*)xraw;
        for (int idx = t; idx < 32 * 25; idx += 256) {
            int node = idx / 25, k4 = idx % 25;
            ushort4 u = xu[(size_t)(nb + node) * 25 + k4];
            xs[(k4 * 4 + 0) * NTP + node] = __uint_as_float((unsigned)u.x << 16);
            xs[(k4 * 4 + 1) * NTP + node] = __uint_as_float((unsigned)u.y << 16);
            xs[(k4 * 4 + 2) * NTP + node] = __uint_as_float((unsigned)u.z << 16);
            xs[(k4 * 4 + 3) * NTP + node] = __uint_as_float((unsigned)u.w << 16);
        }
    }
    __syncthreads();
    // phase 1: ax = relu(x @ aeW + aeb), kept in LDS transposed
    {
        int j = t & 31, g0 = t >> 5;  // 8 groups x 4 nodes
        float a0 = 0.f, a1 = 0.f, a2 = 0.f, a3 = 0.f;
        #pragma unroll 10
        for (int k = 0; k < 100; k++) {
            float w = aeW[k * 32 + j];
            const float4 xv = *(const float4*)&xs[k * NTP + g0 * 4];
            a0 += w * xv.x; a1 += w * xv.y; a2 += w * xv.z; a3 += w * xv.w;
        }
        float bj = aeb[j];
        axs[j * NTP + g0 * 4 + 0] = fmaxf(a0 + bj, 0.f);
        axs[j * NTP + g0 * 4 + 1] = fmaxf(a1 + bj, 0.f);
        axs[j * NTP + g0 * 4 + 2] = fmaxf(a2 + bj, 0.f);
        axs[j * NTP + g0 * 4 + 3] = fmaxf(a3 + bj, 0.f);
    }
    __syncthreads();
    // phase 2: dual linear 32 -> 128 (2 W-cols/thread), xl->fp16, xr->fp32
    {
        int j = t & 63, g0 = t >> 6;   // cols j, j+64; 4 node groups
        float aL0[2][4], aL1[2][4], aR0[2][4], aR1[2][4];
        #pragma unroll
        for (int g = 0; g < 2; g++)
            #pragma unroll
            for (int c = 0; c < 4; c++) { aL0[g][c]=0.f; aL1[g][c]=0.f; aR0[g][c]=0.f; aR1[g][c]=0.f; }
        #pragma unroll 4
        for (int k = 0; k < 32; k++) {
            float wl0 = Wl[k * 128 + j];
            float wl1 = Wl[k * 128 + j + 64];
            float wr0 = Wr[k * 128 + j];
            float wr1 = Wr[k * 128 + j + 64];
            #pragma unroll
            for (int g = 0; g < 2; g++) {
                const float4 xv = *(const float4*)&axs[k * NTP + (g0 + g * 4) * 4];
                aL0[g][0] += wl0 * xv.x; aL0[g][1] += wl0 * xv.y; aL0[g][2] += wl0 * xv.z; aL0[g][3] += wl0 * xv.w;
                aL1[g][0] += wl1 * xv.x; aL1[g][1] += wl1 * xv.y; aL1[g][2] += wl1 * xv.z; aL1[g][3] += wl1 * xv.w;
                aR0[g][0] += wr0 * xv.x; aR0[g][1] += wr0 * xv.y; aR0[g][2] += wr0 * xv.z; aR0[g][3] += wr0 * xv.w;
                aR1[g][0] += wr1 * xv.x; aR1[g][1] += wr1 * xv.y; aR1[g][2] += wr1 * xv.z; aR1[g][3] += wr1 * xv.w;
            }
        }
        float bl0 = bl[j], bl1 = bl[j + 64], br0 = br[j], br1 = br[j + 64];
        #pragma unroll
        for (int g = 0; g < 2; g++) {
            int n0 = nb + (g0 + g * 4) * 4;
            #pragma unroll
            for (int c = 0; c < 4; c++) {
                size_t row = (size_t)(n0 + c) * 128;
                outl[row + j]      = __float2half(aL0[g][c] + bl0);
                outl[row + j + 64] = __float2half(aL1[g][c] + bl1);
                outr[row + j]      = aR0[g][c] + br0;
                outr[row + j + 64] = aR1[g][c] + br1;
            }
        }
    }
}

// ===== dual linear FOUT=128, 2 W-cols/thread; xl->fp16, xr->fp32 =============
template <int FIN, int NT>
__launch_bounds__(256)
__global__ void k_lin2w(const float* __restrict__ x,
                        const float* __restrict__ Wl, const float* __restrict__ bl,
                        const float* __restrict__ Wr, const float* __restrict__ br,
                        __half* __restrict__ outl, float* __restrict__ outr) {
    constexpr int NTP = NT + 4;
    constexpr int GPT = (NT / 4) / 4;
    __shared__ float xs[FIN * NTP];
    int t = threadIdx.x, nb = blockIdx.x * NT;

    const float4* x4 = (const float4*)x;
    for (int idx = t; idx < NT * (FIN / 4); idx += 256) {
        int node = idx / (FIN / 4), k4 = idx % (FIN / 4);
        float4 v = x4[(size_t)(nb + node) * (FIN / 4) + k4];
        xs[(k4 * 4 + 0) * NTP + node] = v.x;
        xs[(k4 * 4 + 1) * NTP + node] = v.y;
        xs[(k4 * 4 + 2) * NTP + node] = v.z;
        xs[(k4 * 4 + 3) * NTP + node] = v.w;
    }
    __syncthreads();

    int j = t & 63, g0 = t >> 6;
    float aL0[GPT][4], aL1[GPT][4], aR0[GPT][4], aR1[GPT][4];
    #pragma unroll
    for (int g = 0; g < GPT; g++)
        #pragma unroll
        for (int c = 0; c < 4; c++) { aL0[g][c]=0.f; aL1[g][c]=0.f; aR0[g][c]=0.f; aR1[g][c]=0.f; }

    #pragma unroll 4
    for (int k = 0; k < FIN; k++) {
        float wl0 = Wl[(size_t)k * 128 + j];
        float wl1 = Wl[(size_t)k * 128 + j + 64];
        float wr0 = Wr[(size_t)k * 128 + j];
        float wr1 = Wr[(size_t)k * 128 + j + 64];
        #pragma unroll
        for (int g = 0; g < GPT; g++) {
            const float4 xv = *(const float4*)&xs[k * NTP + (g0 + g * 4) * 4];
            aL0[g][0] += wl0 * xv.x; aL0[g][1] += wl0 * xv.y; aL0[g][2] += wl0 * xv.z; aL0[g][3] += wl0 * xv.w;
            aL1[g][0] += wl1 * xv.x; aL1[g][1] += wl1 * xv.y; aL1[g][2] += wl1 * xv.z; aL1[g][3] += wl1 * xv.w;
            aR0[g][0] += wr0 * xv.x; aR0[g][1] += wr0 * xv.y; aR0[g][2] += wr0 * xv.z; aR0[g][3] += wr0 * xv.w;
            aR1[g][0] += wr1 * xv.x; aR1[g][1] += wr1 * xv.y; aR1[g][2] += wr1 * xv.z; aR1[g][3] += wr1 * xv.w;
        }
    }

    float bl0 = bl[j], bl1 = bl[j + 64], br0 = br[j], br1 = br[j + 64];
    #pragma unroll
    for (int g = 0; g < GPT; g++) {
        int n0 = nb + (g0 + g * 4) * 4;
        #pragma unroll
        for (int c = 0; c < 4; c++) {
            size_t row = (size_t)(n0 + c) * 128;
            outl[row + j]      = __float2half(aL0[g][c] + bl0);
            outl[row + j + 64] = __float2half(aL1[g][c] + bl1);
            outr[row + j]      = aR0[g][c] + br0;
            outr[row + j + 64] = aR1[g][c] + br1;
        }
    }
}

// ===== dual linear FIN=128, FOUT=32 (global layer); xl->fp16, xr->fp32 =======
__launch_bounds__(256)
__global__ void k_ling(const float* __restrict__ x,
                       const float* __restrict__ Wl, const float* __restrict__ bl,
                       const float* __restrict__ Wr, const float* __restrict__ br,
                       __half* __restrict__ outl, float* __restrict__ outr) {
    constexpr int NT = 32, NTP = 36, FIN = 128;
    __shared__ float xs[FIN * NTP];
    int t = threadIdx.x, nb = blockIdx.x * NT;

    const float4* x4 = (const float4*)x;
    for (int idx = t; idx < NT * 32; idx += 256) {
        int node = idx >> 5, k4 = idx & 31;
        float4 v = x4[(size_t)(nb + node) * 32 + k4];
        xs[(k4 * 4 + 0) * NTP + node] = v.x;
        xs[(k4 * 4 + 1) * NTP + node] = v.y;
        xs[(k4 * 4 + 2) * NTP + node] = v.z;
        xs[(k4 * 4 + 3) * NTP + node] = v.w;
    }
    __syncthreads();

    int j = t & 31, g0 = t >> 5;
    float aL[4], aR[4];
    #pragma unroll
    for (int c = 0; c < 4; c++) { aL[c] = 0.f; aR[c] = 0.f; }

    #pragma unroll 4
    for (int k = 0; k < FIN; k++) {
        float wl = Wl[(size_t)k * 32 + j];
        float wr = Wr[(size_t)k * 32 + j];
        const float4 xv = *(const float4*)&xs[k * NTP + g0 * 4];
        aL[0] += wl * xv.x; aL[1] += wl * xv.y; aL[2] += wl * xv.z; aL[3] += wl * xv.w;
        aR[0] += wr * xv.x; aR[1] += wr * xv.y; aR[2] += wr * xv.z; aR[3] += wr * xv.w;
    }

    float blj = bl[j], brj = br[j];
    #pragma unroll
    for (int c = 0; c < 4; c++) {
        size_t row = (size_t)(nb + g0 * 4 + c) * 32;
        outl[row + j] = __float2half(aL[c] + blj);
        outr[row + j] = aR[c] + brj;
    }
}

// ===== fused GAT H=4: wave/dst, csr in registers, 4 rows in flight ===========
__launch_bounds__(256)
__global__ void k_gat4h(const __half* __restrict__ xl, const float* __restrict__ xr,
                        const float* __restrict__ att,
                        const int* __restrict__ offs, const int* __restrict__ csr,
                        const float* __restrict__ bias, float* __restrict__ out,
                        int N) {
    int wave = threadIdx.x >> 6, lane = threadIdx.x & 63;
    int d = blockIdx.x * 4 + wave;
    if (d >= N) return;
    int grp = lane >> 4, sub = lane & 15;     // 4 edge-groups x 16 lanes
    int i0 = offs[d], i1 = offs[d + 1];

    float xrd[8], av[8], acc[8];
    {
        const float4* p4 = (const float4*)(xr + (size_t)d * 128 + sub * 8);
        float4 a = p4[0], b = p4[1];
        xrd[0]=a.x; xrd[1]=a.y; xrd[2]=a.z; xrd[3]=a.w;
        xrd[4]=b.x; xrd[5]=b.y; xrd[6]=b.z; xrd[7]=b.w;
        const float4* t4 = (const float4*)(att + sub * 8);
        float4 c = t4[0], e = t4[1];
        av[0]=c.x; av[1]=c.y; av[2]=c.z; av[3]=c.w;
        av[4]=e.x; av[5]=e.y; av[6]=e.z; av[7]=e.w;
    }
    #pragma unroll
    for (int c = 0; c < 8; c++) acc[c] = 0.f;
    float sm = 0.f;

    auto proc = [&](float4 raw) {
        const __half2* h = (const __half2*)&raw;
        float v[8];
        float2 f;
        f = __half22float2(h[0]); v[0] = f.x; v[1] = f.y;
        f = __half22float2(h[1]); v[2] = f.x; v[3] = f.y;
        f = __half22float2(h[2]); v[4] = f.x; v[5] = f.y;
        f = __half22float2(h[3]); v[6] = f.x; v[7] = f.y;
        float p = 0.f;
        #pragma unroll
        for (int c = 0; c < 8; c++) {
            float u = v[c] + xrd[c];
            u = (u > 0.f) ? u : NEG_SLOPE * u;
            p += u * av[c];
        }
        p += __shfl_xor(p, 1);
        p += __shfl_xor(p, 2);
        p += __shfl_xor(p, 4);
        p += __shfl_xor(p, 8);
        float w = __expf(fminf(p, 80.f));
        sm += w;
        #pragma unroll
        for (int c = 0; c < 8; c++) acc[c] += w * v[c];
    };

    for (int base = i0; base < i1; base += 64) {
        int cnt = min(i1 - base, 64);
        int myv = (lane < cnt) ? csr[base + lane] : 0;   // whole adjacency chunk, 1 load
        int m16 = cnt >> 4;
        for (int q = 0; q < m16; q++) {
            int b4 = q * 16 + grp;
            int s0 = __shfl(myv, b4);
            int s1 = __shfl(myv, b4 + 4);
            int s2 = __shfl(myv, b4 + 8);
            int s3 = __shfl(myv, b4 + 12);
            float4 r0 = *(const float4*)(xl + (size_t)s0 * 128 + sub * 8);
            float4 r1 = *(const float4*)(xl + (size_t)s1 * 128 + sub * 8);
            float4 r2 = *(const float4*)(xl + (size_t)s2 * 128 + sub * 8);
            float4 r3 = *(const float4*)(xl + (size_t)s3 * 128 + sub * 8);
            proc(r0); proc(r1); proc(r2); proc(r3);
        }
        for (int j = m16 * 16 + grp; j < cnt; j += 4) {
            int s = __shfl(myv, j);
            float4 r = *(const float4*)(xl + (size_t)s * 128 + sub * 8);
            proc(r);
        }
    }

    // merge 4 edge-groups
    sm += __shfl_xor(sm, 16); sm += __shfl_xor(sm, 32);
    #pragma unroll
    for (int c = 0; c < 8; c++) {
        acc[c] += __shfl_xor(acc[c], 16);
        acc[c] += __shfl_xor(acc[c], 32);
    }
    if (grp == 0) {
        float inv = 1.f / (sm + 1e-16f);
        const float4* b4p = (const float4*)(bias + sub * 8);
        float4 b0 = b4p[0], b1 = b4p[1];
        float4 o0, o1;
        o0.x = fmaxf(acc[0] * inv + b0.x, 0.f);
        o0.y = fmaxf(acc[1] * inv + b0.y, 0.f);
        o0.z = fmaxf(acc[2] * inv + b0.z, 0.f);
        o0.w = fmaxf(acc[3] * inv + b0.w, 0.f);
        o1.x = fmaxf(acc[4] * inv + b1.x, 0.f);
        o1.y = fmaxf(acc[5] * inv + b1.y, 0.f);
        o1.z = fmaxf(acc[6] * inv + b1.z, 0.f);
        o1.w = fmaxf(acc[7] * inv + b1.w, 0.f);
        float4* op = (float4*)(out + (size_t)d * 128 + sub * 8);
        op[0] = o0; op[1] = o1;
    }
}

// ===== fused GAT H=1: wave/dst, csr in registers, 2 rows in flight/group =====
__launch_bounds__(256)
__global__ void k_gatgh(const __half* __restrict__ xl, const float* __restrict__ xr,
                        const float* __restrict__ att,
                        const int* __restrict__ offs, const int* __restrict__ csr,
                        const float* __restrict__ bias, float* __restrict__ out,
                        int N) {
    int wave = threadIdx.x >> 6, lane = threadIdx.x & 63;
    int d = blockIdx.x * 4 + wave;
    if (d >= N) return;
    int grp = lane >> 3, sub = lane & 7;      // 8 edge-groups x 8 lanes
    int i0 = offs[d], i1 = offs[d + 1];

    float xrd[4], av[4], acc[4];
    {
        float4 a = *(const float4*)(xr + (size_t)d * 32 + sub * 4);
        xrd[0]=a.x; xrd[1]=a.y; xrd[2]=a.z; xrd[3]=a.w;
        float4 c = *(const float4*)(att + sub * 4);
        av[0]=c.x; av[1]=c.y; av[2]=c.z; av[3]=c.w;
    }
    #pragma unroll
    for (int c = 0; c < 4; c++) acc[c] = 0.f;
    float sm = 0.f;

    auto proc = [&](float2 raw) {
        const __half2* h = (const __half2*)&raw;
        float v[4];
        float2 f;
        f = __half22float2(h[0]); v[0] = f.x; v[1] = f.y;
        f = __half22float2(h[1]); v[2] = f.x; v[3] = f.y;
        float p = 0.f;
        #pragma unroll
        for (int c = 0; c < 4; c++) {
            float u = v[c] + xrd[c];
            u = (u > 0.f) ? u : NEG_SLOPE * u;
            p += u * av[c];
        }
        p += __shfl_xor(p, 1);
        p += __shfl_xor(p, 2);
        p += __shfl_xor(p, 4);
        float w = __expf(fminf(p, 80.f));
        sm += w;
        #pragma unroll
        for (int c = 0; c < 4; c++) acc[c] += w * v[c];
    };

    for (int base = i0; base < i1; base += 64) {
        int cnt = min(i1 - base, 64);
        int myv = (lane < cnt) ? csr[base + lane] : 0;
        int m16 = cnt >> 4;
        for (int q = 0; q < m16; q++) {
            int b8 = q * 16 + grp;
            int s0 = __shfl(myv, b8);
            int s1 = __shfl(myv, b8 + 8);
            float2 r0 = *(const float2*)(xl + (size_t)s0 * 32 + sub * 4);
            float2 r1 = *(const float2*)(xl + (size_t)s1 * 32 + sub * 4);
            proc(r0); proc(r1);
        }
        for (int j = m16 * 16 + grp; j < cnt; j += 8) {
            int s = __shfl(myv, j);
            float2 r = *(const float2*)(xl + (size_t)s * 32 + sub * 4);
            proc(r);
        }
    }

    // merge 8 edge-groups
    sm += __shfl_xor(sm, 8); sm += __shfl_xor(sm, 16); sm += __shfl_xor(sm, 32);
    #pragma unroll
    for (int c = 0; c < 4; c++) {
        acc[c] += __shfl_xor(acc[c], 8);
        acc[c] += __shfl_xor(acc[c], 16);
        acc[c] += __shfl_xor(acc[c], 32);
    }
    if (grp == 0) {
        float inv = 1.f / (sm + 1e-16f);
        float4 b = *(const float4*)(bias + sub * 4);
        float4 o;
        o.x = fmaxf(acc[0] * inv + b.x, 0.f);
        o.y = fmaxf(acc[1] * inv + b.y, 0.f);
        o.z = fmaxf(acc[2] * inv + b.z, 0.f);
        o.w = fmaxf(acc[3] * inv + b.w, 0.f);
        *(float4*)(out + (size_t)d * 32 + sub * 4) = o;
    }
}

// ================= tail =================
__global__ void k_tail(const float* __restrict__ gf, const int* __restrict__ focal,
                       const float* __restrict__ clf, const float* __restrict__ clW,
                       const float* __restrict__ clb, const float* __restrict__ fcW,
                       const float* __restrict__ fcb, void* __restrict__ out,
                       const int* __restrict__ flag) {
    int b = blockIdx.x;
    int t = threadIdx.x;
    __shared__ float comb[64];
    __shared__ float ssum[2];
    if (t < 2) {
        float s = 0.f;
        for (int l = 0; l < 50; l++) s += clf[(size_t)b * 100 + l * 2 + t];
        ssum[t] = s / 50.f;
    }
    if (t < 32) comb[t] = gf[(size_t)focal[b] * 32 + t];
    __syncthreads();
    if (t < 32) comb[32 + t] = ssum[0] * clW[t] + ssum[1] * clW[32 + t] + clb[t];
    __syncthreads();
    if (t < 60) {
        float acc = fcb[t];
        #pragma unroll 16
        for (int k = 0; k < 64; k++) acc += comb[k] * fcW[k * 60 + t];
        if (flag[0]) ((float*)out)[b * 60 + t] = acc;
        else ((bf16*)out)[b * 60 + t] = __float2bfloat16(acc);
    }
}

extern "C" void kernel_launch(void* const* d_in, const int* in_sizes, int n_in,
                              void* d_out, int out_size, void* d_ws, size_t ws_size,
                              hipStream_t stream) {
    const int* edge  = (const int*)d_in[1];
    const int* focal = (const int*)d_in[5];

    const int N = in_sizes[0] / 100;   // 20000
    const int E = in_sizes[1] / 2;     // 320000
    const int B = in_sizes[5];         // 64
    const int EA = E + N;
    const int* srcArr = edge;
    const int* dstArr = edge + E;

    // ---- conversion table: weights + centerlines -> fp32 in ws (x stays raw)
    const int idxs[NSEG] = {7,8,9,10,11,12,13,14,15,16,17,18,19,20,
                            35,36,37,38,39,40,41,42,43,44, 6};
    float* base = (float*)d_ws;
    int* flag = (int*)base;            // base[0..15] reserved
    float* wf = base + 16;
    Tab tab;
    int off[NSEG];
    int o = 0;
    for (int i = 0; i < NSEG; i++) {
        tab.s[i].src = d_in[idxs[i]];
        tab.s[i].n   = in_sizes[idxs[i]];
        tab.s[i].off = o;
        off[i] = o;
        o += in_sizes[idxs[i]];
    }
    const float* aeW  = wf + off[0],  *aeb  = wf + off[1];
    const float* a1Wl = wf + off[2],  *a1bl = wf + off[3];
    const float* a1Wr = wf + off[4],  *a1br = wf + off[5];
    const float* a1att= wf + off[6],  *a1b  = wf + off[7];
    const float* a2Wl = wf + off[8],  *a2bl = wf + off[9];
    const float* a2Wr = wf + off[10], *a2br = wf + off[11];
    const float* a2att= wf + off[12], *a2b  = wf + off[13];
    const float* clW  = wf + off[14], *clb  = wf + off[15];
    const float* gWl  = wf + off[16], *gbl  = wf + off[17];
    const float* gWr  = wf + off[18], *gbr  = wf + off[19];
    const float* gatt = wf + off[20], *gb   = wf + off[21];
    const float* fcW  = wf + off[22], *fcb  = wf + off[23];
    const float* clf  = wf + off[24];

    // ---- remaining workspace (keep 16B alignment) ----
    float* p = wf + o + ((4 - (o & 3)) & 3);
    size_t N128 = (size_t)N * 128;
    __half* hxl = (__half*)p;       p += (size_t)N * 64;    // xl fp16 [N,128]
    float* fB  = p;                 p += N128;              // xr fp32 (global: xrg+gf)
    float* fC  = p;                 p += N128;              // h / agent_features fp32
    int* deg    = (int*)p;          // [N]
    int* cursor = deg + N;          // [N]
    int* st     = cursor + N;       // [32] scan lookback state
    int* offs   = st + 32;          // N+1
    int* csr    = offs + N + 1;     // EA (src node ids)

    const int NB = (N + 1023) / 1024;          // scan tiles (20)
    const int EB = N / 32;                     // embedlin blocks (625)
    const int FBLK = (EA + 255) / 256;         // fill blocks

    // ---- detect + zero deg/cursor/st ----
    k_detect_zero<<<64, 256, 0, stream>>>((const unsigned short*)d_in[0], flag, deg, 2 * N + 32);
    // ---- convert weights + count degrees ----
    k_convert<<<256, 256, 0, stream>>>(tab, wf, flag, dstArr, E, N, deg);
    // ---- single-kernel lookback scan ----
    k_scanf<<<NB, 1024, 0, stream>>>(deg, offs, N, st, NB);
    // ---- CSR fill + fused embed+conv1-linear in one launch ----
    k_fill_embedlin<<<EB + FBLK, 256, 0, stream>>>(srcArr, dstArr, E, N, offs, cursor, csr,
                                                   d_in[0], flag, aeW, aeb,
                                                   a1Wl, a1bl, a1Wr, a1br, hxl, fB, EB);
    // ---- conv1 gather ----
    k_gat4h<<<(N + 3) / 4, 256, 0, stream>>>(hxl, fB, a1att, offs, csr, a1b, fC, N);
    // ---- conv2 ----
    k_lin2w<128, 32><<<N / 32, 256, 0, stream>>>(fC, a2Wl, a2bl, a2Wr, a2br, hxl, fB);
    k_gat4h<<<(N + 3) / 4, 256, 0, stream>>>(hxl, fB, a2att, offs, csr, a2b, fC, N);
    // ---- global graph (heads=1) ----
    float* xrg = fB;
    float* gf  = fB + (size_t)N * 32;
    k_ling<<<N / 32, 256, 0, stream>>>(fC, gWl, gbl, gWr, gbr, hxl, xrg);
    k_gatgh<<<(N + 3) / 4, 256, 0, stream>>>(hxl, xrg, gatt, offs, csr, gb, gf, N);
    // ---- tail ----
    k_tail<<<B, 64, 0, stream>>>(gf, focal, clf, clW, clb, fcW, fcb, d_out, flag);
}